// Round 1
// baseline (85.593 us; speedup 1.0000x reference)
//
#include <hip/hip_runtime.h>
#include <hip/hip_bf16.h>
#include <math.h>

// ComplexEMA: y[b,d,l] = sum_n Re(gp[d,n] * s[n,l]) + omega[d]*x[b,d,l]
//   s[n,l] = q[d,n]*s[n,l-1] + x[b,d,l],  q = radius*exp(i*phi), |q|<1
// Equivalent to the reference's FFT convolution (linear conv with a
// sum-of-geometric-series kernel), computed exactly via chunked parallel scan.

#define B 8
#define D 1024
#define L 2048
#define NM 16
#define CHUNK 32          // positions per lane (L / 64 lanes)
#define LROW 2112         // 64 chunks * 33 floats (pad +1 per 32 -> bank-conflict-free)

__global__ void coeff_kernel(const float* __restrict__ alpha,
                             const float* __restrict__ delta,
                             const float* __restrict__ theta,
                             const float* __restrict__ gamma_r,
                             const float* __restrict__ gamma_i,
                             float4* __restrict__ coef) {
    int idx = blockIdx.x * blockDim.x + threadIdx.x;   // (d,n) flat, 0..16383
    if (idx >= D * NM) return;
    int d = idx >> 4;
    int n = idx & 15;
    float a  = 1.0f / (1.0f + __expf(-alpha[idx]));
    float dd = 1.0f / (1.0f + __expf(-delta[idx]));
    float th = (1.0f / (1.0f + __expf(-theta[d]))) * (2.0f * 3.14159265358979323846f / (float)NM);
    float phi = (float)(n + 1) * th;
    float radius = fminf(1.0f - a * dd, 1.0f);
    float sn, cs;
    __sincosf(phi, &sn, &cs);
    float scale = 0.25f * a;                  // sqrt(1/N)=0.25 times p=a
    coef[idx] = make_float4(radius * cs, radius * sn,
                            gamma_r[idx] * scale, gamma_i[idx] * scale);
}

__global__ __launch_bounds__(256) void ema_kernel(const float* __restrict__ x,
                                                  const float4* __restrict__ coef,
                                                  const float* __restrict__ omega,
                                                  float* __restrict__ out) {
    __shared__ float lds[4 * LROW];
    const int tid  = threadIdx.x;
    const int wave = tid >> 6;
    const int lane = tid & 63;
    const size_t blockBase = (size_t)blockIdx.x * (4 * L);   // 4 rows per block

    // ---- stage x -> LDS (coalesced float4 global reads, padded scalar LDS writes)
    {
        const float4* xv = (const float4*)(x + blockBase);
        #pragma unroll
        for (int k = 0; k < 8; ++k) {
            int g4 = tid + 256 * k;          // float4 index within block's 8192 floats
            float4 v = xv[g4];
            int g   = g4 << 2;               // element index
            int row = g >> 11;               // which of 4 rows
            int l   = g & (L - 1);
            int li  = row * LROW + ((l >> 5) * 33) + (l & 31);
            lds[li + 0] = v.x; lds[li + 1] = v.y; lds[li + 2] = v.z; lds[li + 3] = v.w;
        }
    }
    __syncthreads();

    const int rowIdx = blockIdx.x * 4 + wave;   // global (b,d) row
    const int d = rowIdx & (D - 1);

    // ---- per-mode coefficients (wave-uniform, L1-served)
    float qr[NM], qi[NM], gr[NM], gin[NM];
    {
        const float4* cf = coef + d * NM;
        #pragma unroll
        for (int n = 0; n < NM; ++n) {
            float4 c = cf[n];
            qr[n] = c.x; qi[n] = c.y; gr[n] = c.z; gin[n] = -c.w;
        }
    }
    const float om = omega[d];

    float* xrow = lds + wave * LROW;
    const int cbase = lane * 33;

    // ---- pass 1: chunk-local end states (zero init)
    float sr[NM], si[NM];
    #pragma unroll
    for (int n = 0; n < NM; ++n) { sr[n] = 0.0f; si[n] = 0.0f; }
    for (int j = 0; j < CHUNK; ++j) {
        float xv = xrow[cbase + j];
        #pragma unroll
        for (int n = 0; n < NM; ++n) {
            float tr = fmaf(qr[n], sr[n], fmaf(-qi[n], si[n], xv));
            float ti = fmaf(qr[n], si[n], qi[n] * sr[n]);
            sr[n] = tr; si[n] = ti;
        }
    }

    // ---- Kogge-Stone inclusive scan across 64 lanes, weight w = q^CHUNK
    float wr[NM], wi[NM];
    #pragma unroll
    for (int n = 0; n < NM; ++n) { wr[n] = qr[n]; wi[n] = qi[n]; }
    #pragma unroll
    for (int t = 0; t < 5; ++t) {            // q -> q^32
        #pragma unroll
        for (int n = 0; n < NM; ++n) {
            float t2 = fmaf(wr[n], wr[n], -(wi[n] * wi[n]));
            wi[n] = 2.0f * wr[n] * wi[n];
            wr[n] = t2;
        }
    }
    #pragma unroll
    for (int k = 1; k <= 32; k <<= 1) {
        #pragma unroll
        for (int n = 0; n < NM; ++n) {
            float or_ = __shfl_up(sr[n], (unsigned)k, 64);
            float oi_ = __shfl_up(si[n], (unsigned)k, 64);
            if (lane >= k) {
                sr[n] = fmaf(wr[n], or_, fmaf(-wi[n], oi_, sr[n]));
                si[n] = fmaf(wr[n], oi_, fmaf(wi[n], or_, si[n]));
            }
        }
        if (k != 32) {
            #pragma unroll
            for (int n = 0; n < NM; ++n) {   // w -> w^2 for next distance
                float t2 = fmaf(wr[n], wr[n], -(wi[n] * wi[n]));
                wi[n] = 2.0f * wr[n] * wi[n];
                wr[n] = t2;
            }
        }
    }
    // exclusive: incoming carry for this chunk
    #pragma unroll
    for (int n = 0; n < NM; ++n) {
        float cr = __shfl_up(sr[n], 1u, 64);
        float ci = __shfl_up(si[n], 1u, 64);
        sr[n] = (lane == 0) ? 0.0f : cr;
        si[n] = (lane == 0) ? 0.0f : ci;
    }

    // ---- pass 2: rescan with carry, emit y (overwrite x in LDS)
    for (int j = 0; j < CHUNK; ++j) {
        float xv = xrow[cbase + j];
        float acc = om * xv;
        #pragma unroll
        for (int n = 0; n < NM; ++n) {
            float tr = fmaf(qr[n], sr[n], fmaf(-qi[n], si[n], xv));
            float ti = fmaf(qr[n], si[n], qi[n] * sr[n]);
            sr[n] = tr; si[n] = ti;
            acc = fmaf(gr[n], tr, acc);
            acc = fmaf(gin[n], ti, acc);
        }
        xrow[cbase + j] = acc;
    }
    __syncthreads();

    // ---- LDS -> global (coalesced float4 writes)
    {
        float4* dst = (float4*)(out + blockBase);
        #pragma unroll
        for (int k = 0; k < 8; ++k) {
            int g4 = tid + 256 * k;
            int g   = g4 << 2;
            int row = g >> 11;
            int l   = g & (L - 1);
            int li  = row * LROW + ((l >> 5) * 33) + (l & 31);
            dst[g4] = make_float4(lds[li], lds[li + 1], lds[li + 2], lds[li + 3]);
        }
    }
}

extern "C" void kernel_launch(void* const* d_in, const int* in_sizes, int n_in,
                              void* d_out, int out_size, void* d_ws, size_t ws_size,
                              hipStream_t stream) {
    const float* x       = (const float*)d_in[0];
    const float* alpha   = (const float*)d_in[1];
    const float* delta   = (const float*)d_in[2];
    const float* theta   = (const float*)d_in[3];
    const float* gamma_r = (const float*)d_in[4];
    const float* gamma_i = (const float*)d_in[5];
    const float* omega   = (const float*)d_in[6];
    float* out = (float*)d_out;
    float4* coef = (float4*)d_ws;            // D*NM float4 = 256 KiB

    coeff_kernel<<<(D * NM + 255) / 256, 256, 0, stream>>>(alpha, delta, theta,
                                                           gamma_r, gamma_i, coef);
    ema_kernel<<<(B * D) / 4, 256, 0, stream>>>(x, coef, omega, out);
}